// Round 7
// baseline (843.179 us; speedup 1.0000x reference)
//
#include <hip/hip_runtime.h>

// ---------------------------------------------------------------------------
// Grid attention v8, bf16 MFMA (gfx950). 4096 windows; n=49; D=512; 16h x 32.
// v6 skeleton (x,y LDS-staged once, 4 wave-pairs, N-split proj / M-split attn,
// deep weight preloads) + LDS-pipe reductions:
//  - fused 2-head Q-pass (A-frag reads halved)
//  - swapped QK^T: sim^T lane=query -> in-reg softmax (2 shfl), normalized
//    P packed uint2 stores, PV B-frags as b128 reads, no sum buffer
//  - q/k store swizzle ((row>>2)&3)<<5: scatter stores 8-way -> 2-way banks
// LDS = 160 KiB exactly: xb 50176 | yb 50176 | 4 pairs x 15872
//   pair: qA 3136 | k 3136 | qB 3136 | vt 4096 ; P(A)=qA+k, P(B)=k+qB
// ws (2.5MB): Wq/Wk/Wv pre-swizzled B-frags + biasT (TRANSPOSED D-layout).
// ---------------------------------------------------------------------------

typedef __bf16 bf16x8 __attribute__((ext_vector_type(8)));
typedef __attribute__((ext_vector_type(4))) float f32x4;

#define DEVI __device__ __forceinline__

DEVI unsigned short f2bf(float f) {  // round-to-nearest-even
  union { float f; unsigned u; } v; v.f = f;
  unsigned r = v.u + 0x7FFFu + ((v.u >> 16) & 1u);
  return (unsigned short)(r >> 16);
}
DEVI unsigned pkbf(float a, float b) {
  return (unsigned)f2bf(a) | ((unsigned)f2bf(b) << 16);
}

#define MFMA16(a, b, c) __builtin_amdgcn_mfma_f32_16x16x32_bf16((a), (b), (c), 0, 0, 0)

#define SWZ_Y(r)  ((((unsigned)(r)) & 7u) << 4)
#define SWZ_A(r)  (((((unsigned)(r)) >> 2) & 3u) << 5)
#define SWZ_P(r)  ((((unsigned)(r)) & 7u) << 4)
#define SWZ_VT(r) ((((unsigned)(r)) & 7u) << 4)

// ---------------- prep: weights -> swizzled bf16 frags, bias -> sim^T layout
__global__ void prep_kernel(const float* __restrict__ Wq, const float* __restrict__ Wkv,
                            const float* __restrict__ bt, char* __restrict__ ws) {
  int t = blockIdx.x * 256 + threadIdx.x;
  if (t < 786432) {  // 3 * 16 * 2 * 16 * 64 * 8 bf16 elements
    int e = t & 7, lane = (t >> 3) & 63, ks = (t >> 9) & 15, nt = (t >> 13) & 1,
        h = (t >> 14) & 15, T = t >> 18;
    int row = ks * 32 + (lane >> 4) * 8 + e;     // K index in [0,512)
    int col = h * 32 + nt * 16 + (lane & 15);    // N index
    float v;
    if (T == 0)      v = Wq[row * 512 + col] * 0.17677669529663687f;  // fold 1/sqrt(32)
    else if (T == 1) v = Wkv[row * 1024 + col];
    else             v = Wkv[row * 1024 + 512 + col];
    ((unsigned short*)ws)[t] = f2bf(v);
  }
  if (t < 262144) {  // 16 * 4(i-tile) * 4(j-tile) * 64 * 4 f32, sim^T layout
    int r = t & 3, lane = (t >> 2) & 63, nt = (t >> 8) & 3, mt = (t >> 10) & 3,
        h = (t >> 12) & 15;
    int i = mt * 16 + (lane & 15);               // query: lane = col of sim^T
    int j = nt * 16 + ((lane >> 4) & 3) * 4 + r; // key: regs = rows of sim^T
    float v;
    if (j >= 49)      v = -1e30f;   // mask padded key columns
    else if (i >= 49) v = 0.0f;     // padded query rows: keep finite
    else {
      int hi = i / 7, wi = i % 7, hj = j / 7, wj = j % 7;
      v = bt[((hi - hj + 6) * 13 + (wi - wj + 6)) * 16 + h];
    }
    ((float*)(ws + 1572864))[t] = v;
  }
}

// ---------------- LDS fragment loaders --------------------------------------
DEVI bf16x8 ldXY(const char* base, int row, int kc) {
  unsigned a = ((unsigned)(row * 1024 + kc * 2)) ^ SWZ_Y(row);
  return *(const bf16x8*)(base + a);
}
DEVI bf16x8 ldXY_c(const char* base, int row, int kc) {
  int rc = row < 48 ? row : 48;
  bf16x8 v = ldXY(base, rc, kc);
  if (row > 48) {
    union { long long z[2]; bf16x8 v; } u; u.z[0] = 0; u.z[1] = 0;
    v = u.v;
  }
  return v;
}
// q/k: [49][32] bf16, row stride 64B, swz SWZ_A
DEVI bf16x8 ldA(const char* base, int row, int kc) {
  int rc = row < 48 ? row : 48;
  unsigned a = ((unsigned)(rc * 64 + kc * 2)) ^ SWZ_A(rc);
  return *(const bf16x8*)(base + a);
}
// P: [49][64] bf16 normalized, row = query i, swz SWZ_P
DEVI bf16x8 ldP2(const char* base, int row, int jc) {
  int rc = row < 48 ? row : 48;
  unsigned a = ((unsigned)(rc * 128 + jc * 2)) ^ SWZ_P(rc);
  return *(const bf16x8*)(base + a);
}
// vt: [32][64] bf16 (V transposed: [dh][tok]), swz SWZ_VT
DEVI bf16x8 ldVT(const char* base, int dh, int jc) {
  unsigned a = ((unsigned)(dh * 128 + jc * 2)) ^ SWZ_VT(dh);
  return *(const bf16x8*)(base + a);
}

// ---------------- main fused kernel ----------------------------------------
__global__ __launch_bounds__(512, 2)
void attn_kernel(const float* __restrict__ x, const float* __restrict__ y,
                 const char* __restrict__ wsW, const float* __restrict__ biasD,
                 float* __restrict__ out) {
  extern __shared__ char smem[];
  char* xb = smem;            // 50176
  char* yb = smem + 50176;    // 50176
  const int tid = threadIdx.x;
  const int lane = tid & 63, wave = tid >> 6;
  const int p = wave >> 1, sub = wave & 1;
  const int g = lane >> 4, lr = lane & 15;
  char* pbase = smem + 100352 + p * 15872;  // per-pair scratch
  char* qAb = pbase;            // 3136
  char* kbuf = pbase + 3136;    // 3136
  char* qBb = pbase + 6272;     // 3136
  char* vt = pbase + 9408;      // 4096
  // P(A) = pbase (qA+k), P(B) = pbase+3136 (k+qB) -- barrier-guarded aliases

  const int bw = blockIdx.x;
  const float* xs = x + (size_t)bw * 25088;
  const float* ys = y + (size_t)bw * 25088;

  // ---- stage x,y windows to LDS as bf16 ----
  for (int it = tid; it < 6272; it += 512) {
    float4 v = ((const float4*)xs)[it];
    float4 w = ((const float4*)ys)[it];
    int i = it >> 7;
    int k = (it & 127) << 2;
    unsigned a = ((unsigned)(i * 1024 + k * 2)) ^ SWZ_Y(i);
    uint2 ux, uy;
    ux.x = pkbf(v.x, v.y); ux.y = pkbf(v.z, v.w);
    uy.x = pkbf(w.x, w.y); uy.y = pkbf(w.z, w.w);
    *(uint2*)(xb + a) = ux;
    *(uint2*)(yb + a) = uy;
  }

  const bf16x8* wsQ = (const bf16x8*)wsW;
  const bf16x8* wsK = (const bf16x8*)(wsW + 524288);
  const bf16x8* wsV = (const bf16x8*)(wsW + 1048576);
  const f32x4* bD = (const f32x4*)biasD;
  const f32x4 fz = {0.f, 0.f, 0.f, 0.f};

  // store q or k (D-layout acc -> [row][dh] u16 scatter, 2-way banks)
  auto storeQK = [&](char* qb, f32x4 (&acc)[4]) {
    #pragma unroll
    for (int mt = 0; mt < 4; ++mt)
      #pragma unroll
      for (int r = 0; r < 4; ++r) {
        int row = mt * 16 + g * 4 + r;
        if (row < 49) {
          unsigned a = ((unsigned)(row * 64 + (sub * 16 + lr) * 2)) ^ SWZ_A(row);
          *(unsigned short*)(qb + a) = f2bf(acc[mt][r]);
        }
      }
  };

  // KV projection compute for head h (N-split col = sub), rolling 8-deep
  auto kv_compute = [&](int h, f32x4 (&ak)[4], f32x4 (&av)[4]) {
    #pragma unroll
    for (int mt = 0; mt < 4; ++mt) { ak[mt] = fz; av[mt] = fz; }
    const bf16x8* pK = wsK + (size_t)((h * 2 + sub) * 16) * 64 + lane;
    const bf16x8* pV = wsV + (size_t)((h * 2 + sub) * 16) * 64 + lane;
    bf16x8 ksr[8], vsr[8];
    #pragma unroll
    for (int i = 0; i < 8; ++i) { ksr[i] = pK[i * 64]; vsr[i] = pV[i * 64]; }
    #pragma unroll
    for (int ks = 0; ks < 16; ++ks) {
      bf16x8 bk = ksr[ks & 7], bv = vsr[ks & 7];
      if (ks < 8) { ksr[ks & 7] = pK[(ks + 8) * 64]; vsr[ks & 7] = pV[(ks + 8) * 64]; }
      int kc = ks * 32 + g * 8;
      bf16x8 a0 = ldXY(yb, lr, kc);
      bf16x8 a1 = ldXY(yb, lr + 16, kc);
      bf16x8 a2 = ldXY(yb, lr + 32, kc);
      bf16x8 a3 = ldXY_c(yb, lr + 48, kc);
      ak[0] = MFMA16(a0, bk, ak[0]);
      ak[1] = MFMA16(a1, bk, ak[1]);
      ak[2] = MFMA16(a2, bk, ak[2]);
      ak[3] = MFMA16(a3, bk, ak[3]);
      av[0] = MFMA16(a0, bv, av[0]);
      av[1] = MFMA16(a1, bv, av[1]);
      av[2] = MFMA16(a2, bv, av[2]);
      av[3] = MFMA16(a3, bv, av[3]);
    }
  };

  auto kv_store = [&](f32x4 (&ak)[4], f32x4 (&av)[4]) {
    storeQK(kbuf, ak);
    #pragma unroll
    for (int mt = 0; mt < 4; ++mt) {
      int dh = sub * 16 + lr;
      int t0 = mt * 16 + g * 4;
      unsigned a = ((unsigned)(dh * 128 + t0 * 2)) ^ SWZ_VT(dh);
      uint2 pk;
      pk.x = pkbf(av[mt][0], av[mt][1]);
      pk.y = pkbf(av[mt][2], av[mt][3]);
      *(uint2*)(vt + a) = pk;
    }
  };

  // attention for head h: swapped QK^T, in-reg softmax, packed P, PV, store.
  // Contains one barrier (P-alias guard).
  auto attn_head = [&](int h, const char* qbuf, char* Pb) {
    f32x4 bias[2][4];
    #pragma unroll
    for (int mi = 0; mi < 2; ++mi)
      #pragma unroll
      for (int nt = 0; nt < 4; ++nt)
        bias[mi][nt] = bD[(size_t)(((h * 4 + sub * 2 + mi) * 4 + nt) * 64 + lane)];

    bf16x8 qa[2], kf[4];
    #pragma unroll
    for (int mi = 0; mi < 2; ++mi) qa[mi] = ldA(qbuf, sub * 32 + mi * 16 + lr, g * 8);
    #pragma unroll
    for (int nt = 0; nt < 4; ++nt) kf[nt] = ldA(kbuf, nt * 16 + lr, g * 8);

    // sim^T tiles: lane&15 = query i (local), regs = key j (g*4+r)
    f32x4 accs[2][4];
    #pragma unroll
    for (int mi = 0; mi < 2; ++mi)
      #pragma unroll
      for (int nt = 0; nt < 4; ++nt)
        accs[mi][nt] = MFMA16(kf[nt], qa[mi], fz);

    // softmax fully per-lane (16 j-values) + 2 shfl for the 4 gg-replicas
    uint2 pks[2][4];
    #pragma unroll
    for (int mi = 0; mi < 2; ++mi) {
      f32x4 vals[4];
      #pragma unroll
      for (int nt = 0; nt < 4; ++nt) vals[nt] = accs[mi][nt] + bias[mi][nt];
      float m = vals[0][0];
      #pragma unroll
      for (int nt = 0; nt < 4; ++nt)
        #pragma unroll
        for (int r = 0; r < 4; ++r) m = fmaxf(m, vals[nt][r]);
      m = fmaxf(m, __shfl_xor(m, 16));
      m = fmaxf(m, __shfl_xor(m, 32));
      float s = 0.f;
      #pragma unroll
      for (int nt = 0; nt < 4; ++nt)
        #pragma unroll
        for (int r = 0; r < 4; ++r) {
          float pv = __expf(vals[nt][r] - m);
          vals[nt][r] = pv;
          s += pv;
        }
      s += __shfl_xor(s, 16);
      s += __shfl_xor(s, 32);
      float inv = 1.0f / s;
      #pragma unroll
      for (int nt = 0; nt < 4; ++nt) {
        pks[mi][nt].x = pkbf(vals[nt][0] * inv, vals[nt][1] * inv);
        pks[mi][nt].y = pkbf(vals[nt][2] * inv, vals[nt][3] * inv);
      }
    }

    __syncthreads();  // partner's q/k reads done -> P may overwrite alias region

    #pragma unroll
    for (int mi = 0; mi < 2; ++mi) {
      int i = sub * 32 + mi * 16 + lr;
      if (i < 49) {
        #pragma unroll
        for (int nt = 0; nt < 4; ++nt) {
          unsigned a = ((unsigned)(i * 128 + (nt * 16 + g * 4) * 2)) ^ SWZ_P(i);
          *(uint2*)(Pb + a) = pks[mi][nt];
        }
      }
    }

    // PV: out^T[dh][i] = V^T @ P^T ; A = vt rows dh, B = P rows (own queries)
    f32x4 acco[2][2];
    acco[0][0] = fz; acco[0][1] = fz; acco[1][0] = fz; acco[1][1] = fz;
    #pragma unroll
    for (int ks = 0; ks < 2; ++ks) {
      int jc = ks * 32 + g * 8;
      bf16x8 av0 = ldVT(vt, lr, jc);
      bf16x8 av1 = ldVT(vt, lr + 16, jc);
      bf16x8 bp0 = ldP2(Pb, sub * 32 + lr, jc);
      bf16x8 bp1 = ldP2(Pb, sub * 32 + 16 + lr, jc);
      acco[0][0] = MFMA16(av0, bp0, acco[0][0]);
      acco[0][1] = MFMA16(av0, bp1, acco[0][1]);
      acco[1][0] = MFMA16(av1, bp0, acco[1][0]);
      acco[1][1] = MFMA16(av1, bp1, acco[1][1]);
    }

    float* ow = out + (size_t)bw * 25088 + h * 32;
    #pragma unroll
    for (int it = 0; it < 2; ++it) {
      int tok = sub * 32 + it * 16 + lr;
      if (tok < 49) {
        #pragma unroll
        for (int dt = 0; dt < 2; ++dt)
          *(f32x4*)(&ow[(size_t)tok * 512 + dt * 16 + g * 4]) = acco[dt][it];
      }
    }
  };

  for (int hp = 0; hp < 2; ++hp) {
    const int hA = p * 4 + hp * 2, hB = hA + 1;

    __syncthreads();  // prior readers of pair scratch done (or staging done)

    // ---- fused Q-pass for hA+hB (shared A-frags), rolling 8-deep x 2 ----
    f32x4 aqA[4], aqB[4];
    #pragma unroll
    for (int mt = 0; mt < 4; ++mt) { aqA[mt] = fz; aqB[mt] = fz; }
    {
      const bf16x8* pQA = wsQ + (size_t)((hA * 2 + sub) * 16) * 64 + lane;
      const bf16x8* pQB = wsQ + (size_t)((hB * 2 + sub) * 16) * 64 + lane;
      bf16x8 ra[8], rb[8];
      #pragma unroll
      for (int i = 0; i < 8; ++i) { ra[i] = pQA[i * 64]; rb[i] = pQB[i * 64]; }
      #pragma unroll
      for (int ks = 0; ks < 16; ++ks) {
        bf16x8 fa = ra[ks & 7], fb = rb[ks & 7];
        if (ks < 8) { ra[ks & 7] = pQA[(ks + 8) * 64]; rb[ks & 7] = pQB[(ks + 8) * 64]; }
        int kc = ks * 32 + g * 8;
        bf16x8 a0 = ldXY(xb, lr, kc);
        bf16x8 a1 = ldXY(xb, lr + 16, kc);
        bf16x8 a2 = ldXY(xb, lr + 32, kc);
        bf16x8 a3 = ldXY_c(xb, lr + 48, kc);
        aqA[0] = MFMA16(a0, fa, aqA[0]);
        aqA[1] = MFMA16(a1, fa, aqA[1]);
        aqA[2] = MFMA16(a2, fa, aqA[2]);
        aqA[3] = MFMA16(a3, fa, aqA[3]);
        aqB[0] = MFMA16(a0, fb, aqB[0]);
        aqB[1] = MFMA16(a1, fb, aqB[1]);
        aqB[2] = MFMA16(a2, fb, aqB[2]);
        aqB[3] = MFMA16(a3, fb, aqB[3]);
      }
    }
    storeQK(qAb, aqA);
    storeQK(qBb, aqB);

    // ---- KV(hA) ----
    {
      f32x4 ak[4], av[4];
      kv_compute(hA, ak, av);
      kv_store(ak, av);
    }

    __syncthreads();  // qA, qB, kA, vtA visible

    attn_head(hA, qAb, pbase);           // P(A) over qA+k (internal barrier)

    // ---- KV(hB): compute early (no scratch writes), store after guard ----
    {
      f32x4 ak[4], av[4];
      kv_compute(hB, ak, av);
      __syncthreads();  // partner PV(A) done: P(A), vtA dead
      kv_store(ak, av);
    }

    __syncthreads();  // kB, vtB visible

    attn_head(hB, qBb, pbase + 3136);    // P(B) over k+qB (internal barrier)
  }
}

extern "C" void kernel_launch(void* const* d_in, const int* in_sizes, int n_in,
                              void* d_out, int out_size, void* d_ws, size_t ws_size,
                              hipStream_t stream) {
  (void)in_sizes; (void)n_in; (void)out_size; (void)ws_size;
  const float* x = (const float*)d_in[0];
  const float* y = (const float*)d_in[1];
  const float* Wq = (const float*)d_in[2];
  const float* Wkv = (const float*)d_in[3];
  const float* bt = (const float*)d_in[4];
  float* out = (float*)d_out;
  char* ws = (char*)d_ws;

  prep_kernel<<<3072, 256, 0, stream>>>(Wq, Wkv, bt, ws);

  (void)hipFuncSetAttribute((const void*)attn_kernel,
                            hipFuncAttributeMaxDynamicSharedMemorySize, 163840);
  attn_kernel<<<4096, 512, 163840, stream>>>(x, y, (const char*)ws,
                                             (const float*)(ws + 1572864), out);
}